// Round 7
// baseline (357.059 us; speedup 1.0000x reference)
//
#include <hip/hip_runtime.h>

#define B 4
#define S 2048
#define H 16
#define DK 64
#define DM 1024
#define NTILES (S / 64)
#define QSCALE 0.18033688011112042f   // 0.125 * log2(e); folded into Q projection

typedef _Float16 half_t;
typedef __attribute__((ext_vector_type(8))) _Float16 half8v;   // 8 fp16 = MFMA A/B frag
typedef __attribute__((ext_vector_type(2))) _Float16 half2v;
typedef __attribute__((ext_vector_type(2))) __fp16   fp16x2;   // builtin return type
typedef __attribute__((ext_vector_type(4))) float    float4v;  // MFMA C/D frag

// pack two fp32 -> fp16x2 RTZ in one v_cvt_pkrtz (bias cancels in softmax O/l)
__device__ __forceinline__ unsigned pkh(float lo, float hi) {
    union { fp16x2 h; unsigned u; } cvt;
    cvt.h = __builtin_amdgcn_cvt_pkrtz(lo, hi);
    return cvt.u;
}
__device__ __forceinline__ float fast_exp2(float x) {
#if __has_builtin(__builtin_amdgcn_exp2f)
    return __builtin_amdgcn_exp2f(x);
#else
    return __expf(x * 0.69314718055994531f);
#endif
}
// convert 8 fp32 (two float4, consecutive k) -> fp16 frag (RNE v_cvt_f16_f32)
__device__ __forceinline__ half8v cvt8h(float4 a, float4 b) {
    half8v r;
    r[0] = (half_t)a.x; r[1] = (half_t)a.y; r[2] = (half_t)a.z; r[3] = (half_t)a.w;
    r[4] = (half_t)b.x; r[5] = (half_t)b.y; r[6] = (half_t)b.z; r[7] = (half_t)b.w;
    return r;
}
// async global -> LDS, 16B per lane. LDS dest = wave-uniform base + lane*16.
__device__ __forceinline__ void gl2lds16(const void* g, void* l) {
    __builtin_amdgcn_global_load_lds(
        (const __attribute__((address_space(1))) unsigned int*)g,
        (__attribute__((address_space(3))) unsigned int*)l, 16, 0, 0);
}

// ---------------------------------------------------------------------------
// Kernel 0: pack mask (S,S) int32 -> 1 bit per element.
// ---------------------------------------------------------------------------
__global__ __launch_bounds__(256) void mask_pack_kernel(
    const int* __restrict__ mask, unsigned long long* __restrict__ mp)
{
    int t = blockIdx.x * 256 + threadIdx.x;
    int m = mask[t];
    unsigned long long b = __ballot(m != 0);
    if ((threadIdx.x & 63) == 0) mp[t >> 6] = b;
}

// ---------------------------------------------------------------------------
// Kernel 0b: convert Wo fp32 -> fp16 (one-time, mem-bound, RNE).
// ---------------------------------------------------------------------------
__global__ __launch_bounds__(256) void wcvt_kernel(
    const float* __restrict__ Wo, half_t* __restrict__ Wh)
{
    int t = (blockIdx.x * 256 + threadIdx.x) * 4;
    float4 wv = *(const float4*)(Wo + t);
    union { half_t h[4]; uint2 u; } cvt;
    cvt.h[0] = (half_t)wv.x; cvt.h[1] = (half_t)wv.y;
    cvt.h[2] = (half_t)wv.z; cvt.h[3] = (half_t)wv.w;
    *(uint2*)(Wh + t) = cvt.u;
}

// ---------------------------------------------------------------------------
// Kernel 1: QKV projection via fp16 MFMA. Zero LDS, zero barriers.
// y=0: V -> Vt (B,H,64,S) with PV-permuted columns; y=1: K; y=2: Q (scaled).
// ---------------------------------------------------------------------------
__global__ __launch_bounds__(256) void qkv_proj_kernel(
    const float* __restrict__ xv, const float* __restrict__ xk, const float* __restrict__ xq,
    const float* __restrict__ Wv, const float* __restrict__ Wk, const float* __restrict__ Wq,
    half_t* __restrict__ vtw, half_t* __restrict__ kw, half_t* __restrict__ qw)
{
    const int y = blockIdx.y;
    const float* x; const float* W;
    if (y == 0)      { x = xv; W = Wv; }
    else if (y == 1) { x = xk; W = Wk; }
    else             { x = xq; W = Wq; }

    const int tid = threadIdx.x;
    const int w = tid >> 6, L = tid & 63, a = L & 15, g = L >> 4;
    const int bx  = blockIdx.x;
    const int st  = bx & 31;
    const int bh  = bx >> 5;
    const int b_  = bh >> 4, h = bh & 15;
    const int s0b = st * 64;

    // W fragments: lane a <-> dim-row 16t+a, quad g <-> k-chunk
    half8v wF[4][2];
    #pragma unroll
    for (int t = 0; t < 4; ++t)
        #pragma unroll
        for (int c = 0; c < 2; ++c) {
            const float* wr = W + (size_t)(16 * t + a) * 64 + 32 * c + 8 * g;
            wF[t][c] = cvt8h(*(const float4*)wr, *(const float4*)(wr + 4));
        }

    // x fragments: lane a <-> s-row s0b+16w+a
    const float* xr = x + ((size_t)(b_ * S) + s0b + 16 * w + a) * DM + h * 64 + 8 * g;
    half8v xF0 = cvt8h(*(const float4*)(xr),      *(const float4*)(xr + 4));
    half8v xF1 = cvt8h(*(const float4*)(xr + 32), *(const float4*)(xr + 36));

    const float4v z4 = {0.0f, 0.0f, 0.0f, 0.0f};

    if (y == 0) {
        // V^T: A = W (m=d), B = x (n=s). D[m=4g+r][n=a].
        const int c   = 16 * w + a;
        const int pos = 32 * (c >> 5) + 8 * ((c >> 2) & 3) + 4 * ((c >> 4) & 1) + (c & 3);
        #pragma unroll
        for (int mt = 0; mt < 4; ++mt) {
            float4v D = __builtin_amdgcn_mfma_f32_16x16x32_f16(wF[mt][0], xF0, z4, 0, 0, 0);
            D = __builtin_amdgcn_mfma_f32_16x16x32_f16(wF[mt][1], xF1, D, 0, 0, 0);
            #pragma unroll
            for (int r = 0; r < 4; ++r)
                vtw[((size_t)bh * 64 + 16 * mt + 4 * g + r) * S + s0b + pos] = (half_t)D[r];
        }
    } else {
        half_t* out = (y == 1) ? kw : qw;
        const float scale = (y == 2) ? QSCALE : 1.0f;
        #pragma unroll
        for (int nt = 0; nt < 4; ++nt) {
            float4v D = __builtin_amdgcn_mfma_f32_16x16x32_f16(xF0, wF[nt][0], z4, 0, 0, 0);
            D = __builtin_amdgcn_mfma_f32_16x16x32_f16(xF1, wF[nt][1], D, 0, 0, 0);
            #pragma unroll
            for (int r = 0; r < 4; ++r)
                out[((size_t)bh * S + s0b + 16 * w + 4 * g + r) * 64 + 16 * nt + a] =
                    (half_t)(D[r] * scale);
        }
    }
}

// ---------------------------------------------------------------------------
// Kernel 2: flash attention, fp16 MFMA. grid(x=bh, y=qtile) for XCD L2
// locality. K/V staged via global_load_lds with XOR gather swizzle, dbuf.
// p = exp2(st) (Q pre-scaled, shift-free); P packed RTZ via v_cvt_pkrtz;
// l via ones-row MFMA on the packed P (exact bias cancellation).
// Output: single fp16 att array (B,S,DM).
// ---------------------------------------------------------------------------
__global__ __launch_bounds__(256, 4) void flash_attn_kernel(
    const half_t* __restrict__ q, const half_t* __restrict__ k,
    const half_t* __restrict__ vt, const unsigned long long* __restrict__ mp,
    half_t* __restrict__ att)
{
    __shared__ half_t KV[2][2][64 * 64];  // [buf][0=K,1=V][row*8+cp chunks of 8]

    const int tid = threadIdx.x;
    const int w   = tid >> 6;
    const int L   = tid & 63;
    const int a   = L & 15;
    const int g   = L >> 4;
    const int bh  = blockIdx.x;
    const int b_  = bh >> 4, h = bh & 15;
    const int qs  = blockIdx.y * 128 + w * 32;

    const half_t* qb = q  + (size_t)bh * S * 64;
    const half_t* kb = k  + (size_t)bh * S * 64;
    const half_t* vb = vt + (size_t)bh * 64 * S;

    half8v qB[2][2];
    #pragma unroll
    for (int gq = 0; gq < 2; ++gq) {
        const half_t* qr = qb + (size_t)(qs + 16 * gq + a) * 64;
        qB[gq][0] = *(const half8v*)(qr +      g * 8);
        qB[gq][1] = *(const half8v*)(qr + 32 + g * 8);
    }

    const unsigned long long* mr0 = mp + (size_t)(qs      + a) * NTILES;
    const unsigned long long* mr1 = mp + (size_t)(qs + 16 + a) * NTILES;

    int srow[2], schk[2];
    #pragma unroll
    for (int i = 0; i < 2; ++i) {
        int p   = (w * 2 + i) * 64 + L;
        srow[i] = p >> 3;
        schk[i] = (p & 7) ^ (srow[i] & 7);
    }

    half8v ones;
    #pragma unroll
    for (int i = 0; i < 8; ++i) ones[i] = (half_t)1.0f;

    const float4v z4 = {0.0f, 0.0f, 0.0f, 0.0f};
    float4v o[2][4] = {{z4, z4, z4, z4}, {z4, z4, z4, z4}};
    float4v lD[2] = {z4, z4};

    #pragma unroll
    for (int i = 0; i < 2; ++i) {
        gl2lds16(kb + (size_t)srow[i] * 64 + schk[i] * 8, &KV[0][0][(w * 2 + i) * 64 * 8]);
        gl2lds16(vb + (size_t)srow[i] * S + schk[i] * 8,  &KV[0][1][(w * 2 + i) * 64 * 8]);
    }

    for (int kt = 0; kt < NTILES; ++kt) {
        const int cur = kt & 1;
        __syncthreads();   // buf[cur] staged (vmcnt drained) + prev reads done

        if (kt + 1 < NTILES) {
            const int nk = kt + 1;
            #pragma unroll
            for (int i = 0; i < 2; ++i) {
                gl2lds16(kb + ((size_t)(nk * 64 + srow[i])) * 64 + schk[i] * 8,
                         &KV[cur ^ 1][0][(w * 2 + i) * 64 * 8]);
                gl2lds16(vb + (size_t)srow[i] * S + nk * 64 + schk[i] * 8,
                         &KV[cur ^ 1][1][(w * 2 + i) * 64 * 8]);
            }
        }

        const unsigned long long mw0 = mr0[kt];
        const unsigned long long mw1 = mr1[kt];

        const half_t* Kb = &KV[cur][0][0];
        const half_t* Vb = &KV[cur][1][0];

        half8v kB[4][2], vA[4][2];
        #pragma unroll
        for (int nt = 0; nt < 4; ++nt)
            #pragma unroll
            for (int c = 0; c < 2; ++c) {
                const int off = ((16 * nt + a) * 8 + ((4 * c + g) ^ (a & 7))) * 8;
                kB[nt][c] = *(const half8v*)(Kb + off);
                vA[nt][c] = *(const half8v*)(Vb + off);
            }

        #pragma unroll
        for (int gq = 0; gq < 2; ++gq) {
            float4v st[4];
            #pragma unroll
            for (int nt = 0; nt < 4; ++nt) {
                st[nt] = __builtin_amdgcn_mfma_f32_16x16x32_f16(kB[nt][0], qB[gq][0], z4, 0, 0, 0);
                st[nt] = __builtin_amdgcn_mfma_f32_16x16x32_f16(kB[nt][1], qB[gq][1], st[nt], 0, 0, 0);
            }

            const unsigned long long mw = gq ? mw1 : mw0;
            float e[4][4];
            #pragma unroll
            for (int nt = 0; nt < 4; ++nt) {
                unsigned bnt = (unsigned)(mw >> (16 * nt + 4 * g));
                #pragma unroll
                for (int r = 0; r < 4; ++r) {
                    float ee = fast_exp2(st[nt][r]);       // single v_exp_f32
                    e[nt][r] = ((bnt >> r) & 1u) ? ee : 0.0f;
                }
            }

            half8v pB[2];
            #pragma unroll
            for (int c = 0; c < 2; ++c) {
                union { unsigned u[4]; half8v hv; } cvt;
                cvt.u[0] = pkh(e[2*c  ][0], e[2*c  ][1]);
                cvt.u[1] = pkh(e[2*c  ][2], e[2*c  ][3]);
                cvt.u[2] = pkh(e[2*c+1][0], e[2*c+1][1]);
                cvt.u[3] = pkh(e[2*c+1][2], e[2*c+1][3]);
                pB[c] = cvt.hv;
            }

            #pragma unroll
            for (int nt = 0; nt < 4; ++nt) {
                o[gq][nt] = __builtin_amdgcn_mfma_f32_16x16x32_f16(vA[nt][0], pB[0], o[gq][nt], 0, 0, 0);
                o[gq][nt] = __builtin_amdgcn_mfma_f32_16x16x32_f16(vA[nt][1], pB[1], o[gq][nt], 0, 0, 0);
            }
            // l per q-row via ones-row MFMA on the SAME packed P
            lD[gq] = __builtin_amdgcn_mfma_f32_16x16x32_f16(ones, pB[0], lD[gq], 0, 0, 0);
            lD[gq] = __builtin_amdgcn_mfma_f32_16x16x32_f16(ones, pB[1], lD[gq], 0, 0, 0);
        }
    }

    #pragma unroll
    for (int gq = 0; gq < 2; ++gq) {
        const float inv = 1.0f / lD[gq][0];   // all 4 components identical
        const size_t row = (size_t)(b_ * S + qs + 16 * gq + a);
        #pragma unroll
        for (int nt = 0; nt < 4; ++nt) {
            union { unsigned u[2]; uint2 u2; } cvt;
            cvt.u[0] = pkh(o[gq][nt][0] * inv, o[gq][nt][1] * inv);
            cvt.u[1] = pkh(o[gq][nt][2] * inv, o[gq][nt][3] * inv);
            *(uint2*)(att + row * DM + h * 64 + 16 * nt + 4 * g) = cvt.u2;
        }
    }
}

// ---------------------------------------------------------------------------
// Kernel 3: output projection, single-term fp16 MFMA GEMM.
// C(8192x1024) = X(fp16) @ Wo(fp16)^T + bo. 128x128 tile, BK=64,
// global_load_lds + XOR gather swizzle, double-buffered (1 barrier/tile).
// ---------------------------------------------------------------------------
__global__ __launch_bounds__(256, 2) void out_proj_kernel(
    const half_t* __restrict__ X, const half_t* __restrict__ Wh,
    const float* __restrict__ bo, float* __restrict__ out)
{
    __shared__ half_t SA[2][128 * 64], SB[2][128 * 64];   // 64 KB total

    const int tid = threadIdx.x;
    const int w = tid >> 6, L = tid & 63, a = L & 15, g = L >> 4;
    const int wm = w >> 1, wn = w & 1;
    const int r0 = blockIdx.x * 128;
    const int n0 = blockIdx.y * 128;

    int prow[4], pchk[4], pbase[4];
    #pragma unroll
    for (int i = 0; i < 4; ++i) {
        int p    = w * 256 + i * 64 + L;
        prow[i]  = p >> 3;
        pchk[i]  = (p & 7) ^ (prow[i] & 7);
        pbase[i] = (w * 256 + i * 64) * 8;   // fp16-element offset of wave base
    }

    const float4v z4 = {0.0f, 0.0f, 0.0f, 0.0f};
    float4v acc[4][4];
    #pragma unroll
    for (int mt = 0; mt < 4; ++mt)
        #pragma unroll
        for (int nt = 0; nt < 4; ++nt) acc[mt][nt] = z4;

    // stage k-tile 0 into buf 0
    #pragma unroll
    for (int i = 0; i < 4; ++i) {
        gl2lds16(X  + (size_t)(r0 + prow[i]) * DM + pchk[i] * 8, &SA[0][pbase[i]]);
        gl2lds16(Wh + (size_t)(n0 + prow[i]) * DM + pchk[i] * 8, &SB[0][pbase[i]]);
    }

    for (int kt = 0; kt < DM / 64; ++kt) {
        const int cur = kt & 1;
        __syncthreads();   // buf[cur] staged + prev frag reads done

        if (kt + 1 < DM / 64) {
            const int k0 = (kt + 1) * 64;
            #pragma unroll
            for (int i = 0; i < 4; ++i) {
                gl2lds16(X  + (size_t)(r0 + prow[i]) * DM + k0 + pchk[i] * 8, &SA[cur ^ 1][pbase[i]]);
                gl2lds16(Wh + (size_t)(n0 + prow[i]) * DM + k0 + pchk[i] * 8, &SB[cur ^ 1][pbase[i]]);
            }
        }

        half8v bF[4][2];
        #pragma unroll
        for (int nt = 0; nt < 4; ++nt)
            #pragma unroll
            for (int c = 0; c < 2; ++c) {
                const int rb  = 64 * wn + 16 * nt + a;
                const int off = (rb * 8 + ((4 * c + g) ^ (rb & 7))) * 8;
                bF[nt][c] = *(const half8v*)&SB[cur][off];
            }

        #pragma unroll
        for (int mt = 0; mt < 4; ++mt) {
            const int ra   = 64 * wm + 16 * mt + a;
            const int off0 = (ra * 8 + ((0 + g) ^ (ra & 7))) * 8;
            const int off1 = (ra * 8 + ((4 + g) ^ (ra & 7))) * 8;
            half8v a0 = *(const half8v*)&SA[cur][off0];
            half8v a1 = *(const half8v*)&SA[cur][off1];
            #pragma unroll
            for (int nt = 0; nt < 4; ++nt) {
                float4v acv = acc[mt][nt];
                acv = __builtin_amdgcn_mfma_f32_16x16x32_f16(a0, bF[nt][0], acv, 0, 0, 0);
                acv = __builtin_amdgcn_mfma_f32_16x16x32_f16(a1, bF[nt][1], acv, 0, 0, 0);
                acc[mt][nt] = acv;
            }
        }
    }

    #pragma unroll
    for (int mt = 0; mt < 4; ++mt) {
        const int m0 = r0 + 64 * wm + 16 * mt + 4 * g;
        #pragma unroll
        for (int nt = 0; nt < 4; ++nt) {
            const int n = n0 + 64 * wn + 16 * nt + a;
            const float bias = bo[n];
            #pragma unroll
            for (int r = 0; r < 4; ++r)
                out[(size_t)(m0 + r) * DM + n] = acc[mt][nt][r] + bias;
        }
    }
}

// ---------------------------------------------------------------------------
extern "C" void kernel_launch(void* const* d_in, const int* in_sizes, int n_in,
                              void* d_out, int out_size, void* d_ws, size_t ws_size,
                              hipStream_t stream) {
    (void)in_sizes; (void)n_in; (void)out_size; (void)ws_size;
    const float* values = (const float*)d_in[0];
    const float* keys   = (const float*)d_in[1];
    const float* query  = (const float*)d_in[2];
    const int*   mask   = (const int*)d_in[3];
    const float* Wv     = (const float*)d_in[4];
    const float* Wk     = (const float*)d_in[5];
    const float* Wq     = (const float*)d_in[6];
    const float* Wo     = (const float*)d_in[7];
    const float* bo     = (const float*)d_in[8];
    float* out = (float*)d_out;

    const size_t per = (size_t)B * H * S * DK;     // 8,388,608 elements
    half_t* qw  = (half_t*)d_ws;
    half_t* kw  = qw + per;
    half_t* vtw = kw + per;
    unsigned long long* mp = (unsigned long long*)(vtw + per);
    half_t* atth = (half_t*)(mp + (size_t)S * S / 64);
    half_t* woh  = atth + per;                     // B*S*DM == per

    mask_pack_kernel<<<S * S / 256, 256, 0, stream>>>(mask, mp);
    wcvt_kernel<<<DM * DM / 1024, 256, 0, stream>>>(Wo, woh);

    dim3 g1(B * H * (S / 64), 3);
    qkv_proj_kernel<<<g1, 256, 0, stream>>>(values, keys, query, Wv, Wk, Wq, vtw, kw, qw);

    dim3 g2(B * H, S / 128);   // x=bh -> blockId%8 = head%8 (XCD L2 locality)
    flash_attn_kernel<<<g2, 256, 0, stream>>>(qw, kw, vtw, mp, atth);

    dim3 g3(B * S / 128, DM / 128);
    out_proj_kernel<<<g3, 256, 0, stream>>>(atth, woh, bo, out);
}

// Round 8
// 328.091 us; speedup vs baseline: 1.0883x; 1.0883x over previous
//
#include <hip/hip_runtime.h>

#define B 4
#define S 2048
#define H 16
#define DK 64
#define DM 1024
#define NTILES (S / 64)
#define QSCALE 0.18033688011112042f   // 0.125 * log2(e); folded into Q projection

typedef _Float16 half_t;
typedef __attribute__((ext_vector_type(8))) _Float16 half8v;   // 8 fp16 = MFMA A/B frag
typedef __attribute__((ext_vector_type(2))) __fp16   fp16x2;   // builtin return type
typedef __attribute__((ext_vector_type(4))) float    float4v;  // MFMA C/D frag

// pack two fp32 -> fp16x2 RTZ in one v_cvt_pkrtz (bias cancels in softmax O/l)
__device__ __forceinline__ unsigned pkh(float lo, float hi) {
    union { fp16x2 h; unsigned u; } cvt;
    cvt.h = __builtin_amdgcn_cvt_pkrtz(lo, hi);
    return cvt.u;
}
__device__ __forceinline__ float fast_exp2(float x) {
#if __has_builtin(__builtin_amdgcn_exp2f)
    return __builtin_amdgcn_exp2f(x);
#else
    return __expf(x * 0.69314718055994531f);
#endif
}
// convert 8 fp32 (two float4, consecutive k) -> fp16 frag (RNE v_cvt_f16_f32)
__device__ __forceinline__ half8v cvt8h(float4 a, float4 b) {
    half8v r;
    r[0] = (half_t)a.x; r[1] = (half_t)a.y; r[2] = (half_t)a.z; r[3] = (half_t)a.w;
    r[4] = (half_t)b.x; r[5] = (half_t)b.y; r[6] = (half_t)b.z; r[7] = (half_t)b.w;
    return r;
}
// async global -> LDS, 16B per lane. LDS dest = wave-uniform base + lane*16.
__device__ __forceinline__ void gl2lds16(const void* g, void* l) {
    __builtin_amdgcn_global_load_lds(
        (const __attribute__((address_space(1))) unsigned int*)g,
        (__attribute__((address_space(3))) unsigned int*)l, 16, 0, 0);
}

// ---------------------------------------------------------------------------
// Kernel 0: fused prep. Blocks [0, S*S/256): pack mask bits.
// Blocks [S*S/256, +DM*DM/1024): convert Wo fp32 -> fp16.
// ---------------------------------------------------------------------------
#define MASK_BLOCKS (S * S / 256)
__global__ __launch_bounds__(256) void prep_kernel(
    const int* __restrict__ mask, unsigned long long* __restrict__ mp,
    const float* __restrict__ Wo, half_t* __restrict__ Wh)
{
    int bx = blockIdx.x;
    if (bx < MASK_BLOCKS) {
        int t = bx * 256 + threadIdx.x;
        int m = mask[t];
        unsigned long long b = __ballot(m != 0);
        if ((threadIdx.x & 63) == 0) mp[t >> 6] = b;
    } else {
        int t = ((bx - MASK_BLOCKS) * 256 + threadIdx.x) * 4;
        float4 wv = *(const float4*)(Wo + t);
        union { half_t h[4]; uint2 u; } cvt;
        cvt.h[0] = (half_t)wv.x; cvt.h[1] = (half_t)wv.y;
        cvt.h[2] = (half_t)wv.z; cvt.h[3] = (half_t)wv.w;
        *(uint2*)(Wh + t) = cvt.u;
    }
}

// ---------------------------------------------------------------------------
// Kernel 1: QKV projection via fp16 MFMA. Zero LDS, zero barriers.
// y=0: V -> Vt (B,H,64,S) with PV-permuted columns; y=1: K; y=2: Q (scaled).
// ---------------------------------------------------------------------------
__global__ __launch_bounds__(256) void qkv_proj_kernel(
    const float* __restrict__ xv, const float* __restrict__ xk, const float* __restrict__ xq,
    const float* __restrict__ Wv, const float* __restrict__ Wk, const float* __restrict__ Wq,
    half_t* __restrict__ vtw, half_t* __restrict__ kw, half_t* __restrict__ qw)
{
    const int y = blockIdx.y;
    const float* x; const float* W;
    if (y == 0)      { x = xv; W = Wv; }
    else if (y == 1) { x = xk; W = Wk; }
    else             { x = xq; W = Wq; }

    const int tid = threadIdx.x;
    const int w = tid >> 6, L = tid & 63, a = L & 15, g = L >> 4;
    const int bx  = blockIdx.x;
    const int st  = bx & 31;
    const int bh  = bx >> 5;
    const int b_  = bh >> 4, h = bh & 15;
    const int s0b = st * 64;

    // W fragments: lane a <-> dim-row 16t+a, quad g <-> k-chunk
    half8v wF[4][2];
    #pragma unroll
    for (int t = 0; t < 4; ++t)
        #pragma unroll
        for (int c = 0; c < 2; ++c) {
            const float* wr = W + (size_t)(16 * t + a) * 64 + 32 * c + 8 * g;
            wF[t][c] = cvt8h(*(const float4*)wr, *(const float4*)(wr + 4));
        }

    // x fragments: lane a <-> s-row s0b+16w+a
    const float* xr = x + ((size_t)(b_ * S) + s0b + 16 * w + a) * DM + h * 64 + 8 * g;
    half8v xF0 = cvt8h(*(const float4*)(xr),      *(const float4*)(xr + 4));
    half8v xF1 = cvt8h(*(const float4*)(xr + 32), *(const float4*)(xr + 36));

    const float4v z4 = {0.0f, 0.0f, 0.0f, 0.0f};

    if (y == 0) {
        // V^T: A = W (m=d), B = x (n=s). D[m=4g+r][n=a].
        const int c   = 16 * w + a;
        const int pos = 32 * (c >> 5) + 8 * ((c >> 2) & 3) + 4 * ((c >> 4) & 1) + (c & 3);
        #pragma unroll
        for (int mt = 0; mt < 4; ++mt) {
            float4v D = __builtin_amdgcn_mfma_f32_16x16x32_f16(wF[mt][0], xF0, z4, 0, 0, 0);
            D = __builtin_amdgcn_mfma_f32_16x16x32_f16(wF[mt][1], xF1, D, 0, 0, 0);
            #pragma unroll
            for (int r = 0; r < 4; ++r)
                vtw[((size_t)bh * 64 + 16 * mt + 4 * g + r) * S + s0b + pos] = (half_t)D[r];
        }
    } else {
        half_t* out = (y == 1) ? kw : qw;
        const float scale = (y == 2) ? QSCALE : 1.0f;
        #pragma unroll
        for (int nt = 0; nt < 4; ++nt) {
            float4v D = __builtin_amdgcn_mfma_f32_16x16x32_f16(xF0, wF[nt][0], z4, 0, 0, 0);
            D = __builtin_amdgcn_mfma_f32_16x16x32_f16(xF1, wF[nt][1], D, 0, 0, 0);
            #pragma unroll
            for (int r = 0; r < 4; ++r)
                out[((size_t)bh * S + s0b + 16 * w + 4 * g + r) * 64 + 16 * nt + a] =
                    (half_t)(D[r] * scale);
        }
    }
}

// ---------------------------------------------------------------------------
// Kernel 2: flash attention, fp16 MFMA, 256 q-rows/block (wave owns 64 rows
// in 4 groups of 16) -> K/V staging amortized 2x vs 128-row blocks.
// grid(x=bh, y=qtile) for XCD L2 head locality. K/V staged via
// global_load_lds + XOR gather swizzle, double-buffered, 1 barrier/tile.
// p = exp2(st) (Q pre-scaled, shift-free); P packed RTZ via v_cvt_pkrtz;
// l via ones-row MFMA on packed P (exact bias cancellation).
// ---------------------------------------------------------------------------
__global__ __launch_bounds__(256) void flash_attn_kernel(
    const half_t* __restrict__ q, const half_t* __restrict__ k,
    const half_t* __restrict__ vt, const unsigned long long* __restrict__ mp,
    half_t* __restrict__ att)
{
    __shared__ half_t KV[2][2][64 * 64];  // [buf][0=K,1=V][row*8+cp chunks of 8]

    const int tid = threadIdx.x;
    const int w   = tid >> 6;
    const int L   = tid & 63;
    const int a   = L & 15;
    const int g   = L >> 4;
    const int bh  = blockIdx.x;
    const int b_  = bh >> 4, h = bh & 15;
    const int qs  = blockIdx.y * 256 + w * 64;   // wave's 64 q-rows

    const half_t* qb = q  + (size_t)bh * S * 64;
    const half_t* kb = k  + (size_t)bh * S * 64;
    const half_t* vb = vt + (size_t)bh * 64 * S;

    half8v qB[4][2];
    #pragma unroll
    for (int gq = 0; gq < 4; ++gq) {
        const half_t* qr = qb + (size_t)(qs + 16 * gq + a) * 64;
        qB[gq][0] = *(const half8v*)(qr +      g * 8);
        qB[gq][1] = *(const half8v*)(qr + 32 + g * 8);
    }

    const unsigned long long* mr[4];
    #pragma unroll
    for (int gq = 0; gq < 4; ++gq)
        mr[gq] = mp + (size_t)(qs + 16 * gq + a) * NTILES;

    int srow[2], schk[2];
    #pragma unroll
    for (int i = 0; i < 2; ++i) {
        int p   = (w * 2 + i) * 64 + L;
        srow[i] = p >> 3;
        schk[i] = (p & 7) ^ (srow[i] & 7);
    }

    half8v ones;
    #pragma unroll
    for (int i = 0; i < 8; ++i) ones[i] = (half_t)1.0f;

    const float4v z4 = {0.0f, 0.0f, 0.0f, 0.0f};
    float4v o[4][4];
    #pragma unroll
    for (int gq = 0; gq < 4; ++gq)
        #pragma unroll
        for (int nt = 0; nt < 4; ++nt) o[gq][nt] = z4;
    float4v lD[4] = {z4, z4, z4, z4};

    #pragma unroll
    for (int i = 0; i < 2; ++i) {
        gl2lds16(kb + (size_t)srow[i] * 64 + schk[i] * 8, &KV[0][0][(w * 2 + i) * 64 * 8]);
        gl2lds16(vb + (size_t)srow[i] * S + schk[i] * 8,  &KV[0][1][(w * 2 + i) * 64 * 8]);
    }

    for (int kt = 0; kt < NTILES; ++kt) {
        const int cur = kt & 1;
        __syncthreads();   // buf[cur] staged (vmcnt drained) + prev reads done

        if (kt + 1 < NTILES) {
            const int nk = kt + 1;
            #pragma unroll
            for (int i = 0; i < 2; ++i) {
                gl2lds16(kb + ((size_t)(nk * 64 + srow[i])) * 64 + schk[i] * 8,
                         &KV[cur ^ 1][0][(w * 2 + i) * 64 * 8]);
                gl2lds16(vb + (size_t)srow[i] * S + nk * 64 + schk[i] * 8,
                         &KV[cur ^ 1][1][(w * 2 + i) * 64 * 8]);
            }
        }

        unsigned long long mw[4];
        #pragma unroll
        for (int gq = 0; gq < 4; ++gq) mw[gq] = mr[gq][kt];

        const half_t* Kb = &KV[cur][0][0];
        const half_t* Vb = &KV[cur][1][0];

        half8v kB[4][2], vA[4][2];
        #pragma unroll
        for (int nt = 0; nt < 4; ++nt)
            #pragma unroll
            for (int c = 0; c < 2; ++c) {
                const int off = ((16 * nt + a) * 8 + ((4 * c + g) ^ (a & 7))) * 8;
                kB[nt][c] = *(const half8v*)(Kb + off);
                vA[nt][c] = *(const half8v*)(Vb + off);
            }

        #pragma unroll
        for (int gq = 0; gq < 4; ++gq) {
            float4v st[4];
            #pragma unroll
            for (int nt = 0; nt < 4; ++nt) {
                st[nt] = __builtin_amdgcn_mfma_f32_16x16x32_f16(kB[nt][0], qB[gq][0], z4, 0, 0, 0);
                st[nt] = __builtin_amdgcn_mfma_f32_16x16x32_f16(kB[nt][1], qB[gq][1], st[nt], 0, 0, 0);
            }

            float e[4][4];
            #pragma unroll
            for (int nt = 0; nt < 4; ++nt) {
                unsigned bnt = (unsigned)(mw[gq] >> (16 * nt + 4 * g));
                #pragma unroll
                for (int r = 0; r < 4; ++r) {
                    float ee = fast_exp2(st[nt][r]);       // single v_exp_f32
                    e[nt][r] = ((bnt >> r) & 1u) ? ee : 0.0f;
                }
            }

            half8v pB[2];
            #pragma unroll
            for (int c = 0; c < 2; ++c) {
                union { unsigned u[4]; half8v hv; } cvt;
                cvt.u[0] = pkh(e[2*c  ][0], e[2*c  ][1]);
                cvt.u[1] = pkh(e[2*c  ][2], e[2*c  ][3]);
                cvt.u[2] = pkh(e[2*c+1][0], e[2*c+1][1]);
                cvt.u[3] = pkh(e[2*c+1][2], e[2*c+1][3]);
                pB[c] = cvt.hv;
            }

            #pragma unroll
            for (int nt = 0; nt < 4; ++nt) {
                o[gq][nt] = __builtin_amdgcn_mfma_f32_16x16x32_f16(vA[nt][0], pB[0], o[gq][nt], 0, 0, 0);
                o[gq][nt] = __builtin_amdgcn_mfma_f32_16x16x32_f16(vA[nt][1], pB[1], o[gq][nt], 0, 0, 0);
            }
            // l per q-row via ones-row MFMA on the SAME packed P
            lD[gq] = __builtin_amdgcn_mfma_f32_16x16x32_f16(ones, pB[0], lD[gq], 0, 0, 0);
            lD[gq] = __builtin_amdgcn_mfma_f32_16x16x32_f16(ones, pB[1], lD[gq], 0, 0, 0);
        }
    }

    #pragma unroll
    for (int gq = 0; gq < 4; ++gq) {
        const float inv = 1.0f / lD[gq][0];   // all 4 components identical
        const size_t row = (size_t)(b_ * S + qs + 16 * gq + a);
        #pragma unroll
        for (int nt = 0; nt < 4; ++nt) {
            union { unsigned u[2]; uint2 u2; } cvt;
            cvt.u[0] = pkh(o[gq][nt][0] * inv, o[gq][nt][1] * inv);
            cvt.u[1] = pkh(o[gq][nt][2] * inv, o[gq][nt][3] * inv);
            *(uint2*)(att + row * DM + h * 64 + 16 * nt + 4 * g) = cvt.u2;
        }
    }
}

// ---------------------------------------------------------------------------
// Kernel 3: output projection, single-term fp16 MFMA GEMM.
// C(8192x1024) = X(fp16) @ Wo(fp16)^T + bo. 128x128 tile, BK=64,
// global_load_lds + XOR gather swizzle, double-buffered (1 barrier/tile).
// ---------------------------------------------------------------------------
__global__ __launch_bounds__(256, 2) void out_proj_kernel(
    const half_t* __restrict__ X, const half_t* __restrict__ Wh,
    const float* __restrict__ bo, float* __restrict__ out)
{
    __shared__ half_t SA[2][128 * 64], SB[2][128 * 64];   // 64 KB total

    const int tid = threadIdx.x;
    const int w = tid >> 6, L = tid & 63, a = L & 15, g = L >> 4;
    const int wm = w >> 1, wn = w & 1;
    const int r0 = blockIdx.x * 128;
    const int n0 = blockIdx.y * 128;

    int prow[4], pchk[4], pbase[4];
    #pragma unroll
    for (int i = 0; i < 4; ++i) {
        int p    = w * 256 + i * 64 + L;
        prow[i]  = p >> 3;
        pchk[i]  = (p & 7) ^ (prow[i] & 7);
        pbase[i] = (w * 256 + i * 64) * 8;   // fp16-element offset of wave base
    }

    const float4v z4 = {0.0f, 0.0f, 0.0f, 0.0f};
    float4v acc[4][4];
    #pragma unroll
    for (int mt = 0; mt < 4; ++mt)
        #pragma unroll
        for (int nt = 0; nt < 4; ++nt) acc[mt][nt] = z4;

    // stage k-tile 0 into buf 0
    #pragma unroll
    for (int i = 0; i < 4; ++i) {
        gl2lds16(X  + (size_t)(r0 + prow[i]) * DM + pchk[i] * 8, &SA[0][pbase[i]]);
        gl2lds16(Wh + (size_t)(n0 + prow[i]) * DM + pchk[i] * 8, &SB[0][pbase[i]]);
    }

    for (int kt = 0; kt < DM / 64; ++kt) {
        const int cur = kt & 1;
        __syncthreads();   // buf[cur] staged + prev frag reads done

        if (kt + 1 < DM / 64) {
            const int k0 = (kt + 1) * 64;
            #pragma unroll
            for (int i = 0; i < 4; ++i) {
                gl2lds16(X  + (size_t)(r0 + prow[i]) * DM + k0 + pchk[i] * 8, &SA[cur ^ 1][pbase[i]]);
                gl2lds16(Wh + (size_t)(n0 + prow[i]) * DM + k0 + pchk[i] * 8, &SB[cur ^ 1][pbase[i]]);
            }
        }

        half8v bF[4][2];
        #pragma unroll
        for (int nt = 0; nt < 4; ++nt)
            #pragma unroll
            for (int c = 0; c < 2; ++c) {
                const int rb  = 64 * wn + 16 * nt + a;
                const int off = (rb * 8 + ((4 * c + g) ^ (rb & 7))) * 8;
                bF[nt][c] = *(const half8v*)&SB[cur][off];
            }

        #pragma unroll
        for (int mt = 0; mt < 4; ++mt) {
            const int ra   = 64 * wm + 16 * mt + a;
            const int off0 = (ra * 8 + ((0 + g) ^ (ra & 7))) * 8;
            const int off1 = (ra * 8 + ((4 + g) ^ (ra & 7))) * 8;
            half8v a0 = *(const half8v*)&SA[cur][off0];
            half8v a1 = *(const half8v*)&SA[cur][off1];
            #pragma unroll
            for (int nt = 0; nt < 4; ++nt) {
                float4v acv = acc[mt][nt];
                acv = __builtin_amdgcn_mfma_f32_16x16x32_f16(a0, bF[nt][0], acv, 0, 0, 0);
                acv = __builtin_amdgcn_mfma_f32_16x16x32_f16(a1, bF[nt][1], acv, 0, 0, 0);
                acc[mt][nt] = acv;
            }
        }
    }

    #pragma unroll
    for (int mt = 0; mt < 4; ++mt) {
        const int m0 = r0 + 64 * wm + 16 * mt + 4 * g;
        #pragma unroll
        for (int nt = 0; nt < 4; ++nt) {
            const int n = n0 + 64 * wn + 16 * nt + a;
            const float bias = bo[n];
            #pragma unroll
            for (int r = 0; r < 4; ++r)
                out[(size_t)(m0 + r) * DM + n] = acc[mt][nt][r] + bias;
        }
    }
}

// ---------------------------------------------------------------------------
extern "C" void kernel_launch(void* const* d_in, const int* in_sizes, int n_in,
                              void* d_out, int out_size, void* d_ws, size_t ws_size,
                              hipStream_t stream) {
    (void)in_sizes; (void)n_in; (void)out_size; (void)ws_size;
    const float* values = (const float*)d_in[0];
    const float* keys   = (const float*)d_in[1];
    const float* query  = (const float*)d_in[2];
    const int*   mask   = (const int*)d_in[3];
    const float* Wv     = (const float*)d_in[4];
    const float* Wk     = (const float*)d_in[5];
    const float* Wq     = (const float*)d_in[6];
    const float* Wo     = (const float*)d_in[7];
    const float* bo     = (const float*)d_in[8];
    float* out = (float*)d_out;

    const size_t per = (size_t)B * H * S * DK;     // 8,388,608 elements
    half_t* qw  = (half_t*)d_ws;
    half_t* kw  = qw + per;
    half_t* vtw = kw + per;
    unsigned long long* mp = (unsigned long long*)(vtw + per);
    half_t* atth = (half_t*)(mp + (size_t)S * S / 64);
    half_t* woh  = atth + per;                     // B*S*DM == per

    prep_kernel<<<MASK_BLOCKS + DM * DM / 1024, 256, 0, stream>>>(mask, mp, Wo, woh);

    dim3 g1(B * H * (S / 64), 3);
    qkv_proj_kernel<<<g1, 256, 0, stream>>>(values, keys, query, Wv, Wk, Wq, vtw, kw, qw);

    dim3 g2(B * H, S / 256);   // x=bh -> blockId%8 = head%8 (XCD L2 locality)
    flash_attn_kernel<<<g2, 256, 0, stream>>>(qw, kw, vtw, mp, atth);

    dim3 g3(B * S / 128, DM / 128);
    out_proj_kernel<<<g3, 256, 0, stream>>>(atth, woh, bo, out);
}

// Round 9
// 312.217 us; speedup vs baseline: 1.1436x; 1.0508x over previous
//
#include <hip/hip_runtime.h>

#define B 4
#define S 2048
#define H 16
#define DK 64
#define DM 1024
#define NTILES (S / 64)
#define QSCALE 0.18033688011112042f   // 0.125 * log2(e); folded into Q projection

typedef _Float16 half_t;
typedef __attribute__((ext_vector_type(8))) _Float16 half8v;   // 8 fp16 = MFMA A/B frag
typedef __attribute__((ext_vector_type(2))) __fp16   fp16x2;   // builtin return type
typedef __attribute__((ext_vector_type(4))) float    float4v;  // MFMA C/D frag

// pack two fp32 -> fp16x2 RTZ in one v_cvt_pkrtz (bias cancels in softmax O/l)
__device__ __forceinline__ unsigned pkh(float lo, float hi) {
    union { fp16x2 h; unsigned u; } cvt;
    cvt.h = __builtin_amdgcn_cvt_pkrtz(lo, hi);
    return cvt.u;
}
__device__ __forceinline__ float fast_exp2(float x) {
#if __has_builtin(__builtin_amdgcn_exp2f)
    return __builtin_amdgcn_exp2f(x);
#else
    return __expf(x * 0.69314718055994531f);
#endif
}
// convert 8 fp32 (two float4, consecutive k) -> fp16 frag (RNE v_cvt_f16_f32)
__device__ __forceinline__ half8v cvt8h(float4 a, float4 b) {
    half8v r;
    r[0] = (half_t)a.x; r[1] = (half_t)a.y; r[2] = (half_t)a.z; r[3] = (half_t)a.w;
    r[4] = (half_t)b.x; r[5] = (half_t)b.y; r[6] = (half_t)b.z; r[7] = (half_t)b.w;
    return r;
}
// async global -> LDS, 16B per lane. LDS dest = wave-uniform base + lane*16.
__device__ __forceinline__ void gl2lds16(const void* g, void* l) {
    __builtin_amdgcn_global_load_lds(
        (const __attribute__((address_space(1))) unsigned int*)g,
        (__attribute__((address_space(3))) unsigned int*)l, 16, 0, 0);
}

// ---------------------------------------------------------------------------
// Kernel 0: fused prep. Blocks [0, S*S/256): pack mask bits.
// Blocks [S*S/256, +DM*DM/1024): convert Wo fp32 -> fp16.
// ---------------------------------------------------------------------------
#define MASK_BLOCKS (S * S / 256)
__global__ __launch_bounds__(256) void prep_kernel(
    const int* __restrict__ mask, unsigned long long* __restrict__ mp,
    const float* __restrict__ Wo, half_t* __restrict__ Wh)
{
    int bx = blockIdx.x;
    if (bx < MASK_BLOCKS) {
        int t = bx * 256 + threadIdx.x;
        int m = mask[t];
        unsigned long long b = __ballot(m != 0);
        if ((threadIdx.x & 63) == 0) mp[t >> 6] = b;
    } else {
        int t = ((bx - MASK_BLOCKS) * 256 + threadIdx.x) * 4;
        float4 wv = *(const float4*)(Wo + t);
        union { half_t h[4]; uint2 u; } cvt;
        cvt.h[0] = (half_t)wv.x; cvt.h[1] = (half_t)wv.y;
        cvt.h[2] = (half_t)wv.z; cvt.h[3] = (half_t)wv.w;
        *(uint2*)(Wh + t) = cvt.u;
    }
}

// ---------------------------------------------------------------------------
// Kernel 1: QKV projection via fp16 MFMA. Output bounced through padded LDS
// tile (stride 72: 16B-aligned rows, bank-spread) -> two 16B global stores
// per lane instead of 16 scalar 2B stores.
// y=0: V -> Vt (B,H,64,S) with PV-permuted columns; y=1: K; y=2: Q (scaled).
// ---------------------------------------------------------------------------
#define QSTR 72   // LDS bounce-tile stride (halves): 144B rows, 16B aligned
__global__ __launch_bounds__(256) void qkv_proj_kernel(
    const float* __restrict__ xv, const float* __restrict__ xk, const float* __restrict__ xq,
    const float* __restrict__ Wv, const float* __restrict__ Wk, const float* __restrict__ Wq,
    half_t* __restrict__ vtw, half_t* __restrict__ kw, half_t* __restrict__ qw)
{
    __shared__ half_t Ls[64 * QSTR];

    const int y = blockIdx.y;
    const float* x; const float* W;
    if (y == 0)      { x = xv; W = Wv; }
    else if (y == 1) { x = xk; W = Wk; }
    else             { x = xq; W = Wq; }

    const int tid = threadIdx.x;
    const int w = tid >> 6, L = tid & 63, a = L & 15, g = L >> 4;
    const int bx  = blockIdx.x;
    const int st  = bx & 31;
    const int bh  = bx >> 5;
    const int b_  = bh >> 4, h = bh & 15;
    const int s0b = st * 64;

    // W fragments: lane a <-> dim-row 16t+a, quad g <-> k-chunk
    half8v wF[4][2];
    #pragma unroll
    for (int t = 0; t < 4; ++t)
        #pragma unroll
        for (int c = 0; c < 2; ++c) {
            const float* wr = W + (size_t)(16 * t + a) * 64 + 32 * c + 8 * g;
            wF[t][c] = cvt8h(*(const float4*)wr, *(const float4*)(wr + 4));
        }

    // x fragments: lane a <-> s-row s0b+16w+a
    const float* xr = x + ((size_t)(b_ * S) + s0b + 16 * w + a) * DM + h * 64 + 8 * g;
    half8v xF0 = cvt8h(*(const float4*)(xr),      *(const float4*)(xr + 4));
    half8v xF1 = cvt8h(*(const float4*)(xr + 32), *(const float4*)(xr + 36));

    const float4v z4 = {0.0f, 0.0f, 0.0f, 0.0f};

    if (y == 0) {
        // V^T: A = W (m=d), B = x (n=s). D[m=4g+r][n=a]. Ls[d][pos]
        const int c   = 16 * w + a;
        const int pos = 32 * (c >> 5) + 8 * ((c >> 2) & 3) + 4 * ((c >> 4) & 1) + (c & 3);
        #pragma unroll
        for (int mt = 0; mt < 4; ++mt) {
            float4v D = __builtin_amdgcn_mfma_f32_16x16x32_f16(wF[mt][0], xF0, z4, 0, 0, 0);
            D = __builtin_amdgcn_mfma_f32_16x16x32_f16(wF[mt][1], xF1, D, 0, 0, 0);
            #pragma unroll
            for (int r = 0; r < 4; ++r)
                Ls[(16 * mt + 4 * g + r) * QSTR + pos] = (half_t)D[r];
        }
    } else {
        const float scale = (y == 2) ? QSCALE : 1.0f;
        #pragma unroll
        for (int nt = 0; nt < 4; ++nt) {
            float4v D = __builtin_amdgcn_mfma_f32_16x16x32_f16(xF0, wF[nt][0], z4, 0, 0, 0);
            D = __builtin_amdgcn_mfma_f32_16x16x32_f16(xF1, wF[nt][1], D, 0, 0, 0);
            #pragma unroll
            for (int r = 0; r < 4; ++r)
                Ls[(16 * w + 4 * g + r) * QSTR + 16 * nt + a] = (half_t)(D[r] * scale);
        }
    }
    __syncthreads();

    // coalesced copy-out: each thread 16 halves (two 16B stores), 4 threads/row
    const int row = tid >> 2;
    const int col = (tid & 3) * 16;
    uint4 v0 = *(const uint4*)&Ls[row * QSTR + col];
    uint4 v1 = *(const uint4*)&Ls[row * QSTR + col + 8];
    half_t* dst;
    if (y == 0)      dst = vtw + ((size_t)bh * 64 + row) * S + s0b + col;
    else {
        half_t* out = (y == 1) ? kw : qw;
        dst = out + ((size_t)bh * S + s0b + row) * 64 + col;
    }
    *(uint4*)dst = v0;
    *(uint4*)(dst + 8) = v1;
}

// ---------------------------------------------------------------------------
// Kernel 2: flash attention, fp16 MFMA, 256 q-rows/block, 512 THREADS
// (8 waves x 32 rows) -> 16 waves/CU at 2 blocks/CU (2x R8 occupancy, same
// K/V amortization & FETCH). grid(x=bh, y=qtile) for XCD L2 head locality.
// K/V staged via global_load_lds + XOR gather swizzle, double-buffered.
// p = exp2(st) (Q pre-scaled, shift-free); P packed RTZ via v_cvt_pkrtz;
// l via ones-row MFMA on packed P (exact bias cancellation).
// ---------------------------------------------------------------------------
__global__ __launch_bounds__(512) void flash_attn_kernel(
    const half_t* __restrict__ q, const half_t* __restrict__ k,
    const half_t* __restrict__ vt, const unsigned long long* __restrict__ mp,
    half_t* __restrict__ att)
{
    __shared__ half_t KV[2][2][64 * 64];  // [buf][0=K,1=V][row*8+cp chunks of 8]

    const int tid = threadIdx.x;
    const int w   = tid >> 6;            // 0..7
    const int L   = tid & 63;
    const int a   = L & 15;
    const int g   = L >> 4;
    const int bh  = blockIdx.x;
    const int b_  = bh >> 4, h = bh & 15;
    const int qs  = blockIdx.y * 256 + w * 32;   // wave's 32 q-rows

    const half_t* qb = q  + (size_t)bh * S * 64;
    const half_t* kb = k  + (size_t)bh * S * 64;
    const half_t* vb = vt + (size_t)bh * 64 * S;

    half8v qB[2][2];
    #pragma unroll
    for (int gq = 0; gq < 2; ++gq) {
        const half_t* qr = qb + (size_t)(qs + 16 * gq + a) * 64;
        qB[gq][0] = *(const half8v*)(qr +      g * 8);
        qB[gq][1] = *(const half8v*)(qr + 32 + g * 8);
    }

    const unsigned long long* mr[2];
    #pragma unroll
    for (int gq = 0; gq < 2; ++gq)
        mr[gq] = mp + (size_t)(qs + 16 * gq + a) * NTILES;

    // staging: 512 lanes x (1 K-chunk + 1 V-chunk of 8 halves)
    const int p    = w * 64 + L;        // 0..511
    const int srow = p >> 3;
    const int schk = (p & 7) ^ (srow & 7);

    half8v ones;
    #pragma unroll
    for (int i = 0; i < 8; ++i) ones[i] = (half_t)1.0f;

    const float4v z4 = {0.0f, 0.0f, 0.0f, 0.0f};
    float4v o[2][4] = {{z4, z4, z4, z4}, {z4, z4, z4, z4}};
    float4v lD[2] = {z4, z4};

    gl2lds16(kb + (size_t)srow * 64 + schk * 8, &KV[0][0][w * 512]);
    gl2lds16(vb + (size_t)srow * S + schk * 8,  &KV[0][1][w * 512]);

    for (int kt = 0; kt < NTILES; ++kt) {
        const int cur = kt & 1;
        __syncthreads();   // buf[cur] staged (vmcnt drained) + prev reads done

        if (kt + 1 < NTILES) {
            const int nk = kt + 1;
            gl2lds16(kb + ((size_t)(nk * 64 + srow)) * 64 + schk * 8,
                     &KV[cur ^ 1][0][w * 512]);
            gl2lds16(vb + (size_t)srow * S + nk * 64 + schk * 8,
                     &KV[cur ^ 1][1][w * 512]);
        }

        unsigned long long mw[2];
        #pragma unroll
        for (int gq = 0; gq < 2; ++gq) mw[gq] = mr[gq][kt];

        const half_t* Kb = &KV[cur][0][0];
        const half_t* Vb = &KV[cur][1][0];

        half8v kB[4][2], vA[4][2];
        #pragma unroll
        for (int nt = 0; nt < 4; ++nt)
            #pragma unroll
            for (int c = 0; c < 2; ++c) {
                const int off = ((16 * nt + a) * 8 + ((4 * c + g) ^ (a & 7))) * 8;
                kB[nt][c] = *(const half8v*)(Kb + off);
                vA[nt][c] = *(const half8v*)(Vb + off);
            }

        #pragma unroll
        for (int gq = 0; gq < 2; ++gq) {
            float4v st[4];
            #pragma unroll
            for (int nt = 0; nt < 4; ++nt) {
                st[nt] = __builtin_amdgcn_mfma_f32_16x16x32_f16(kB[nt][0], qB[gq][0], z4, 0, 0, 0);
                st[nt] = __builtin_amdgcn_mfma_f32_16x16x32_f16(kB[nt][1], qB[gq][1], st[nt], 0, 0, 0);
            }

            float e[4][4];
            #pragma unroll
            for (int nt = 0; nt < 4; ++nt) {
                unsigned bnt = (unsigned)(mw[gq] >> (16 * nt + 4 * g));
                #pragma unroll
                for (int r = 0; r < 4; ++r) {
                    float ee = fast_exp2(st[nt][r]);       // single v_exp_f32
                    e[nt][r] = ((bnt >> r) & 1u) ? ee : 0.0f;
                }
            }

            half8v pB[2];
            #pragma unroll
            for (int c = 0; c < 2; ++c) {
                union { unsigned u[4]; half8v hv; } cvt;
                cvt.u[0] = pkh(e[2*c  ][0], e[2*c  ][1]);
                cvt.u[1] = pkh(e[2*c  ][2], e[2*c  ][3]);
                cvt.u[2] = pkh(e[2*c+1][0], e[2*c+1][1]);
                cvt.u[3] = pkh(e[2*c+1][2], e[2*c+1][3]);
                pB[c] = cvt.hv;
            }

            #pragma unroll
            for (int nt = 0; nt < 4; ++nt) {
                o[gq][nt] = __builtin_amdgcn_mfma_f32_16x16x32_f16(vA[nt][0], pB[0], o[gq][nt], 0, 0, 0);
                o[gq][nt] = __builtin_amdgcn_mfma_f32_16x16x32_f16(vA[nt][1], pB[1], o[gq][nt], 0, 0, 0);
            }
            // l per q-row via ones-row MFMA on the SAME packed P
            lD[gq] = __builtin_amdgcn_mfma_f32_16x16x32_f16(ones, pB[0], lD[gq], 0, 0, 0);
            lD[gq] = __builtin_amdgcn_mfma_f32_16x16x32_f16(ones, pB[1], lD[gq], 0, 0, 0);
        }
    }

    #pragma unroll
    for (int gq = 0; gq < 2; ++gq) {
        const float inv = 1.0f / lD[gq][0];   // all 4 components identical
        const size_t row = (size_t)(b_ * S + qs + 16 * gq + a);
        #pragma unroll
        for (int nt = 0; nt < 4; ++nt) {
            union { unsigned u[2]; uint2 u2; } cvt;
            cvt.u[0] = pkh(o[gq][nt][0] * inv, o[gq][nt][1] * inv);
            cvt.u[1] = pkh(o[gq][nt][2] * inv, o[gq][nt][3] * inv);
            *(uint2*)(att + row * DM + h * 64 + 16 * nt + 4 * g) = cvt.u2;
        }
    }
}

// ---------------------------------------------------------------------------
// Kernel 3: output projection, single-term fp16 MFMA GEMM.
// C(8192x1024) = X(fp16) @ Wo(fp16)^T + bo. 128x128 tile, BK=64,
// global_load_lds + XOR gather swizzle, double-buffered (1 barrier/tile).
// ---------------------------------------------------------------------------
__global__ __launch_bounds__(256, 2) void out_proj_kernel(
    const half_t* __restrict__ X, const half_t* __restrict__ Wh,
    const float* __restrict__ bo, float* __restrict__ out)
{
    __shared__ half_t SA[2][128 * 64], SB[2][128 * 64];   // 64 KB total

    const int tid = threadIdx.x;
    const int w = tid >> 6, L = tid & 63, a = L & 15, g = L >> 4;
    const int wm = w >> 1, wn = w & 1;
    const int r0 = blockIdx.x * 128;
    const int n0 = blockIdx.y * 128;

    int prow[4], pchk[4], pbase[4];
    #pragma unroll
    for (int i = 0; i < 4; ++i) {
        int p    = w * 256 + i * 64 + L;
        prow[i]  = p >> 3;
        pchk[i]  = (p & 7) ^ (prow[i] & 7);
        pbase[i] = (w * 256 + i * 64) * 8;   // fp16-element offset of wave base
    }

    const float4v z4 = {0.0f, 0.0f, 0.0f, 0.0f};
    float4v acc[4][4];
    #pragma unroll
    for (int mt = 0; mt < 4; ++mt)
        #pragma unroll
        for (int nt = 0; nt < 4; ++nt) acc[mt][nt] = z4;

    // stage k-tile 0 into buf 0
    #pragma unroll
    for (int i = 0; i < 4; ++i) {
        gl2lds16(X  + (size_t)(r0 + prow[i]) * DM + pchk[i] * 8, &SA[0][pbase[i]]);
        gl2lds16(Wh + (size_t)(n0 + prow[i]) * DM + pchk[i] * 8, &SB[0][pbase[i]]);
    }

    for (int kt = 0; kt < DM / 64; ++kt) {
        const int cur = kt & 1;
        __syncthreads();   // buf[cur] staged + prev frag reads done

        if (kt + 1 < DM / 64) {
            const int k0 = (kt + 1) * 64;
            #pragma unroll
            for (int i = 0; i < 4; ++i) {
                gl2lds16(X  + (size_t)(r0 + prow[i]) * DM + k0 + pchk[i] * 8, &SA[cur ^ 1][pbase[i]]);
                gl2lds16(Wh + (size_t)(n0 + prow[i]) * DM + k0 + pchk[i] * 8, &SB[cur ^ 1][pbase[i]]);
            }
        }

        half8v bF[4][2];
        #pragma unroll
        for (int nt = 0; nt < 4; ++nt)
            #pragma unroll
            for (int c = 0; c < 2; ++c) {
                const int rb  = 64 * wn + 16 * nt + a;
                const int off = (rb * 8 + ((4 * c + g) ^ (rb & 7))) * 8;
                bF[nt][c] = *(const half8v*)&SB[cur][off];
            }

        #pragma unroll
        for (int mt = 0; mt < 4; ++mt) {
            const int ra   = 64 * wm + 16 * mt + a;
            const int off0 = (ra * 8 + ((0 + g) ^ (ra & 7))) * 8;
            const int off1 = (ra * 8 + ((4 + g) ^ (ra & 7))) * 8;
            half8v a0 = *(const half8v*)&SA[cur][off0];
            half8v a1 = *(const half8v*)&SA[cur][off1];
            #pragma unroll
            for (int nt = 0; nt < 4; ++nt) {
                float4v acv = acc[mt][nt];
                acv = __builtin_amdgcn_mfma_f32_16x16x32_f16(a0, bF[nt][0], acv, 0, 0, 0);
                acv = __builtin_amdgcn_mfma_f32_16x16x32_f16(a1, bF[nt][1], acv, 0, 0, 0);
                acc[mt][nt] = acv;
            }
        }
    }

    #pragma unroll
    for (int mt = 0; mt < 4; ++mt) {
        const int m0 = r0 + 64 * wm + 16 * mt + 4 * g;
        #pragma unroll
        for (int nt = 0; nt < 4; ++nt) {
            const int n = n0 + 64 * wn + 16 * nt + a;
            const float bias = bo[n];
            #pragma unroll
            for (int r = 0; r < 4; ++r)
                out[(size_t)(m0 + r) * DM + n] = acc[mt][nt][r] + bias;
        }
    }
}

// ---------------------------------------------------------------------------
extern "C" void kernel_launch(void* const* d_in, const int* in_sizes, int n_in,
                              void* d_out, int out_size, void* d_ws, size_t ws_size,
                              hipStream_t stream) {
    (void)in_sizes; (void)n_in; (void)out_size; (void)ws_size;
    const float* values = (const float*)d_in[0];
    const float* keys   = (const float*)d_in[1];
    const float* query  = (const float*)d_in[2];
    const int*   mask   = (const int*)d_in[3];
    const float* Wv     = (const float*)d_in[4];
    const float* Wk     = (const float*)d_in[5];
    const float* Wq     = (const float*)d_in[6];
    const float* Wo     = (const float*)d_in[7];
    const float* bo     = (const float*)d_in[8];
    float* out = (float*)d_out;

    const size_t per = (size_t)B * H * S * DK;     // 8,388,608 elements
    half_t* qw  = (half_t*)d_ws;
    half_t* kw  = qw + per;
    half_t* vtw = kw + per;
    unsigned long long* mp = (unsigned long long*)(vtw + per);
    half_t* atth = (half_t*)(mp + (size_t)S * S / 64);
    half_t* woh  = atth + per;                     // B*S*DM == per

    prep_kernel<<<MASK_BLOCKS + DM * DM / 1024, 256, 0, stream>>>(mask, mp, Wo, woh);

    dim3 g1(B * H * (S / 64), 3);
    qkv_proj_kernel<<<g1, 256, 0, stream>>>(values, keys, query, Wv, Wk, Wq, vtw, kw, qw);

    dim3 g2(B * H, S / 256);   // x=bh -> blockId%8 = head%8 (XCD L2 locality)
    flash_attn_kernel<<<g2, 512, 0, stream>>>(qw, kw, vtw, mp, atth);

    dim3 g3(B * S / 128, DM / 128);
    out_proj_kernel<<<g3, 256, 0, stream>>>(atth, woh, bo, out);
}